// Round 4
// baseline (1641.511 us; speedup 1.0000x reference)
//
#include <hip/hip_runtime.h>

#define N_NODES 100000
#define N_EDGES 1600000
#define NFEAT 128
#define NHID 64
#define N_GRAPHS 64
#define NLAYER 3
#define BN_EPS 1e-5f
#define POOL_SLICES 8

// ---------------------------------------------------------------- zero misc
__global__ void k_zero(float* __restrict__ stats, int* __restrict__ counts,
                       float* __restrict__ out, int* __restrict__ deg) {
    int i = blockIdx.x * 256 + threadIdx.x;
    if (i < 4 * 128) stats[i] = 0.f;
    if (i < N_GRAPHS) counts[i] = 0;
    if (i < N_GRAPHS * NHID) out[i] = 0.f;
    if (i < N_NODES) deg[i] = 0;
}

// ------------------------------------------------- graph counts + edge degs
__global__ void k_count(const int* __restrict__ batch, const int* __restrict__ dst,
                        int* __restrict__ counts, int* __restrict__ deg) {
    int i = blockIdx.x * 256 + threadIdx.x;
    if (i < N_NODES) {
        int g = batch[i];
        g = max(0, min(N_GRAPHS - 1, g));
        atomicAdd(&counts[g], 1);
    }
    if (i < N_EDGES) {
        int d = dst[i];
        d = max(0, min(N_NODES - 1, d));
        atomicAdd(&deg[d], 1);
    }
}

// ------------------------------------------------------- scan node degrees
__global__ __launch_bounds__(1024) void k_scan_nodes(const int* __restrict__ deg,
                                                     int* __restrict__ row_start,
                                                     int* __restrict__ cursor) {
    __shared__ int part[1024];
    __shared__ int base[1025];
    const int CH = (N_NODES + 1023) / 1024;  // 98
    int t = threadIdx.x;
    int lo = t * CH, hi = min(lo + CH, N_NODES);
    int s = 0;
    for (int i = lo; i < hi; ++i) s += deg[i];
    part[t] = s;
    __syncthreads();
    if (t == 0) {
        int acc = 0;
        base[0] = 0;
        for (int i = 0; i < 1024; ++i) { acc += part[i]; base[i + 1] = acc; }
    }
    __syncthreads();
    int acc = base[t];
    for (int i = lo; i < hi; ++i) {
        row_start[i] = acc;
        cursor[i] = acc;
        acc += deg[i];
    }
    if (t == 1023) row_start[N_NODES] = base[1024];
}

// ------------------------------------------------------- scan graph counts
__global__ void k_scan_graphs(const int* __restrict__ counts, int* __restrict__ offs) {
    if (threadIdx.x == 0) {
        int acc = 0;
        for (int g = 0; g < N_GRAPHS; ++g) { offs[g] = acc; acc += counts[g]; }
        offs[N_GRAPHS] = acc;
    }
}

// --------------------------------------------------------------- CSR fill
__global__ void k_fill(const int* __restrict__ src, const int* __restrict__ dst,
                       int* __restrict__ cursor, int* __restrict__ esrc) {
    int e = blockIdx.x * 256 + threadIdx.x;
    if (e < N_EDGES) {
        int d = dst[e];
        d = max(0, min(N_NODES - 1, d));
        int s = src[e];
        s = max(0, min(N_NODES - 1, s));
        int slot = atomicAdd(&cursor[d], 1);
        if (slot >= 0 && slot < N_EDGES) esrc[slot] = s;
    }
}

// ------------------------------------------------------------------- GEMM
// C[M,64] = act(A[M,K] @ W[K,64] + bias), optional relu, optional fused
// column sum/sumsq accumulation into stats[0..63]=sum, stats[64..127]=sumsq.
// block = 256 threads, tile ROWS x 64, per-thread RPT rows x 4 cols.
template <int K, int ROWS, int RPT, bool RELU, bool STATS>
__global__ __launch_bounds__(256) void k_gemm(const float* __restrict__ A,
                                              const float* __restrict__ W,
                                              const float* __restrict__ bias,
                                              float* __restrict__ C,
                                              float* __restrict__ stats, int M) {
    const int ROWP = ROWS + 4;  // pad: conflict-free b128 reads along r
    __shared__ float At[K * ROWP];   // transposed A tile: At[k][r]
    __shared__ float Ws[K * NHID];   // W[k][c]
    __shared__ float sblk[NHID], ssblk[NHID];
    int t = threadIdx.x;
    if (STATS && t < NHID) { sblk[t] = 0.f; ssblk[t] = 0.f; }
    int row0 = blockIdx.x * ROWS;

    // stage W (linear copy, float4)
    for (int i = t; i < K * NHID / 4; i += 256)
        ((float4*)Ws)[i] = ((const float4*)W)[i];

    // stage A transposed
    const int QK = K / 4;
    for (int i = t; i < ROWS * QK; i += 256) {
        int r = i / QK, q = i - r * QK;
        int gr = row0 + r;
        float4 v = make_float4(0.f, 0.f, 0.f, 0.f);
        if (gr < M) v = ((const float4*)(A + (size_t)gr * K))[q];
        At[(4 * q + 0) * ROWP + r] = v.x;
        At[(4 * q + 1) * ROWP + r] = v.y;
        At[(4 * q + 2) * ROWP + r] = v.z;
        At[(4 * q + 3) * ROWP + r] = v.w;
    }
    __syncthreads();

    int c0 = (t & 15) * 4;
    int r0 = (t >> 4) * RPT;
    float acc[RPT][4];
#pragma unroll
    for (int i = 0; i < RPT; ++i) {
        acc[i][0] = 0.f; acc[i][1] = 0.f; acc[i][2] = 0.f; acc[i][3] = 0.f;
    }

#pragma unroll 4
    for (int k = 0; k < K; ++k) {
        float4 w = *(const float4*)&Ws[k * NHID + c0];
#pragma unroll
        for (int ii = 0; ii < RPT / 4; ++ii) {
            float4 a = *(const float4*)&At[k * ROWP + r0 + 4 * ii];
            acc[4 * ii + 0][0] = fmaf(a.x, w.x, acc[4 * ii + 0][0]);
            acc[4 * ii + 0][1] = fmaf(a.x, w.y, acc[4 * ii + 0][1]);
            acc[4 * ii + 0][2] = fmaf(a.x, w.z, acc[4 * ii + 0][2]);
            acc[4 * ii + 0][3] = fmaf(a.x, w.w, acc[4 * ii + 0][3]);
            acc[4 * ii + 1][0] = fmaf(a.y, w.x, acc[4 * ii + 1][0]);
            acc[4 * ii + 1][1] = fmaf(a.y, w.y, acc[4 * ii + 1][1]);
            acc[4 * ii + 1][2] = fmaf(a.y, w.z, acc[4 * ii + 1][2]);
            acc[4 * ii + 1][3] = fmaf(a.y, w.w, acc[4 * ii + 1][3]);
            acc[4 * ii + 2][0] = fmaf(a.z, w.x, acc[4 * ii + 2][0]);
            acc[4 * ii + 2][1] = fmaf(a.z, w.y, acc[4 * ii + 2][1]);
            acc[4 * ii + 2][2] = fmaf(a.z, w.z, acc[4 * ii + 2][2]);
            acc[4 * ii + 2][3] = fmaf(a.z, w.w, acc[4 * ii + 2][3]);
            acc[4 * ii + 3][0] = fmaf(a.w, w.x, acc[4 * ii + 3][0]);
            acc[4 * ii + 3][1] = fmaf(a.w, w.y, acc[4 * ii + 3][1]);
            acc[4 * ii + 3][2] = fmaf(a.w, w.z, acc[4 * ii + 3][2]);
            acc[4 * ii + 3][3] = fmaf(a.w, w.w, acc[4 * ii + 3][3]);
        }
    }

    float4 b4 = *(const float4*)&bias[c0];
    float sp[4] = {0.f, 0.f, 0.f, 0.f};
    float ssp[4] = {0.f, 0.f, 0.f, 0.f};
#pragma unroll
    for (int i = 0; i < RPT; ++i) {
        int gr = row0 + r0 + i;
        if (gr < M) {
            float4 v;
            v.x = acc[i][0] + b4.x;
            v.y = acc[i][1] + b4.y;
            v.z = acc[i][2] + b4.z;
            v.w = acc[i][3] + b4.w;
            if (RELU) {
                v.x = fmaxf(v.x, 0.f); v.y = fmaxf(v.y, 0.f);
                v.z = fmaxf(v.z, 0.f); v.w = fmaxf(v.w, 0.f);
            }
            *(float4*)(C + (size_t)gr * NHID + c0) = v;
            if (STATS) {
                sp[0] += v.x; sp[1] += v.y; sp[2] += v.z; sp[3] += v.w;
                ssp[0] += v.x * v.x; ssp[1] += v.y * v.y;
                ssp[2] += v.z * v.z; ssp[3] += v.w * v.w;
            }
        }
    }

    if (STATS) {
        // lanes l, l+16, l+32, l+48 share the same 4 columns
#pragma unroll
        for (int j = 0; j < 4; ++j) {
            sp[j] += __shfl_down(sp[j], 32);
            sp[j] += __shfl_down(sp[j], 16);
            ssp[j] += __shfl_down(ssp[j], 32);
            ssp[j] += __shfl_down(ssp[j], 16);
        }
        if ((t & 63) < 16) {
#pragma unroll
            for (int j = 0; j < 4; ++j) {
                atomicAdd(&sblk[c0 + j], sp[j]);
                atomicAdd(&ssblk[c0 + j], ssp[j]);
            }
        }
        __syncthreads();
        if (t < NHID) {
            atomicAdd(&stats[t], sblk[t]);
            atomicAdd(&stats[NHID + t], ssblk[t]);
        }
    }
}

// ------------------------------------------------------------ BN normalize
__global__ void k_bn(const float* __restrict__ in, const float* __restrict__ stats,
                     const float* __restrict__ g, const float* __restrict__ b,
                     float* __restrict__ h) {
    int i = blockIdx.x * 256 + threadIdx.x;
    const int n4 = N_NODES * NHID / 4;
    if (i >= n4) return;
    int c4 = i & 15;
    float4 s4 = ((const float4*)stats)[c4];
    float4 q4 = ((const float4*)(stats + NHID))[c4];
    float4 g4 = ((const float4*)g)[c4];
    float4 b4 = ((const float4*)b)[c4];
    const float invN = 1.0f / (float)N_NODES;
    float4 v = ((const float4*)in)[i];
    float4 o;
    {
        float m = s4.x * invN, var = q4.x * invN - m * m;
        o.x = (v.x - m) * rsqrtf(var + BN_EPS) * g4.x + b4.x;
    }
    {
        float m = s4.y * invN, var = q4.y * invN - m * m;
        o.y = (v.y - m) * rsqrtf(var + BN_EPS) * g4.y + b4.y;
    }
    {
        float m = s4.z * invN, var = q4.z * invN - m * m;
        o.z = (v.z - m) * rsqrtf(var + BN_EPS) * g4.z + b4.z;
    }
    {
        float m = s4.w * invN, var = q4.w * invN - m * m;
        o.w = (v.w - m) * rsqrtf(var + BN_EPS) * g4.w + b4.w;
    }
    ((float4*)h)[i] = o;
}

// ------------------------------------------------ gather-based aggregation
// z[i] = h[i] + sum_{e: dst(e)==i} h[src(e)]   (one wave per node, lane=feat)
__global__ __launch_bounds__(256) void k_agg(const float* __restrict__ h,
                                             const int* __restrict__ row_start,
                                             const int* __restrict__ esrc,
                                             float* __restrict__ z) {
    int w = (blockIdx.x * 256 + threadIdx.x) >> 6;
    int l = threadIdx.x & 63;
    if (w >= N_NODES) return;
    int s = row_start[w], e = row_start[w + 1];
    float acc = h[(size_t)w * NHID + l];
    int i = s;
    for (; i + 1 < e; i += 2) {
        int s0 = esrc[i], s1 = esrc[i + 1];
        float a0 = h[(size_t)s0 * NHID + l];
        float a1 = h[(size_t)s1 * NHID + l];
        acc += a0;
        acc += a1;
    }
    if (i < e) acc += h[(size_t)esrc[i] * NHID + l];
    z[(size_t)w * NHID + l] = acc;
}

// ------------------------------------------------------------ mean pooling
// grid = 64 graphs x POOL_SLICES row-slices; accumulates mean into out.
__global__ void k_pool(const float* __restrict__ h, const int* __restrict__ offs,
                       float* __restrict__ out) {
    int g = blockIdx.x & 63;
    int slice = blockIdx.x >> 6;
    int s = offs[g], e = offs[g + 1];
    int f = threadIdx.x & 63, j = threadIdx.x >> 6;
    float acc = 0.f;
    for (int n = s + j + slice * 4; n < e; n += 4 * POOL_SLICES)
        acc += h[(size_t)n * NHID + f];
    __shared__ float red[4][NHID];
    red[j][f] = acc;
    __syncthreads();
    if (threadIdx.x < NHID) {
        float v = red[0][f] + red[1][f] + red[2][f] + red[3][f];
        int cnt = e - s;
        if (cnt > 0) atomicAdd(&out[g * NHID + f], v / (float)cnt);
    }
}

// ------------------------------------------------------------------- host
extern "C" void kernel_launch(void* const* d_in, const int* in_sizes, int n_in,
                              void* d_out, int out_size, void* d_ws, size_t ws_size,
                              hipStream_t stream) {
    const float* x     = (const float*)d_in[0];
    const int*   ei    = (const int*)d_in[1];
    const int*   batch = (const int*)d_in[2];
    const float* W_t   = (const float*)d_in[3];
    const float* b_t   = (const float*)d_in[4];
    const float* bn0_g = (const float*)d_in[5];
    const float* bn0_b = (const float*)d_in[6];
    const float* W1    = (const float*)d_in[7];
    const float* b1    = (const float*)d_in[8];
    const float* W2    = (const float*)d_in[9];
    const float* b2    = (const float*)d_in[10];
    const float* bng   = (const float*)d_in[11];
    const float* bnb   = (const float*)d_in[12];
    float* out = (float*)d_out;

    const size_t NM = (size_t)N_NODES * NHID;
    // workspace layout + size guard (floats then ints)
    const size_t need_bytes =
        (3 * NM + 4 * 128) * sizeof(float) +
        (size_t)(N_GRAPHS + (N_GRAPHS + 1) + N_NODES + (N_NODES + 1) + N_NODES + N_EDGES) *
            sizeof(int);
    if (ws_size < need_bytes) return;  // refuse to corrupt memory

    float* buf0  = (float*)d_ws;
    float* buf1  = buf0 + NM;
    float* buf2  = buf1 + NM;
    float* stats = buf2 + NM;                 // 4 stages x 128 floats
    int* counts    = (int*)(stats + 4 * 128); // 64
    int* offs      = counts + N_GRAPHS;       // 65
    int* deg       = offs + N_GRAPHS + 1;     // N
    int* row_start = deg + N_NODES;           // N+1
    int* cursor    = row_start + N_NODES + 1; // N
    int* esrc      = cursor + N_NODES;        // E

    const int* src = ei;
    const int* dst = ei + N_EDGES;

    // --- setup: zero, counts, scans, CSR fill ---
    k_zero<<<(N_NODES + 255) / 256, 256, 0, stream>>>(stats, counts, out, deg);
    k_count<<<(N_EDGES + 255) / 256, 256, 0, stream>>>(batch, dst, counts, deg);
    k_scan_nodes<<<1, 1024, 0, stream>>>(deg, row_start, cursor);
    k_scan_graphs<<<1, 64, 0, stream>>>(counts, offs);
    k_fill<<<(N_EDGES + 255) / 256, 256, 0, stream>>>(src, dst, cursor, esrc);

    // --- transform: h0 = BN(x @ W_t + b_t) ---
    k_gemm<NFEAT, 64, 4, false, true>
        <<<(N_NODES + 63) / 64, 256, 0, stream>>>(x, W_t, b_t, buf0, stats, N_NODES);
    k_bn<<<(int)(NM / 4 + 255) / 256, 256, 0, stream>>>(buf0, stats, bn0_g, bn0_b, buf1);
    k_pool<<<64 * POOL_SLICES, 256, 0, stream>>>(buf1, offs, out);

    // --- GIN layers ---
    float* A = buf1;   // h
    float* B = buf2;   // scratch
    float* Cb = buf0;  // scratch
    for (int i = 0; i < NLAYER; ++i) {
        k_agg<<<(N_NODES * 64 + 255) / 256, 256, 0, stream>>>(A, row_start, esrc, B);
        k_gemm<NHID, 128, 8, true, false>
            <<<(N_NODES + 127) / 128, 256, 0, stream>>>(B, W1 + i * NHID * NHID,
                                                        b1 + i * NHID, Cb, nullptr, N_NODES);
        k_gemm<NHID, 128, 8, true, true>
            <<<(N_NODES + 127) / 128, 256, 0, stream>>>(Cb, W2 + i * NHID * NHID,
                                                        b2 + i * NHID, B,
                                                        stats + (1 + i) * 128, N_NODES);
        k_bn<<<(int)(NM / 4 + 255) / 256, 256, 0, stream>>>(B, stats + (1 + i) * 128,
                                                            bng + i * NHID, bnb + i * NHID, Cb);
        k_pool<<<64 * POOL_SLICES, 256, 0, stream>>>(Cb, offs, out);
        // rotate: h now in Cb
        float* tmp = A;
        A = Cb;
        Cb = B;
        B = tmp;
    }
}

// Round 5
// 1155.390 us; speedup vs baseline: 1.4207x; 1.4207x over previous
//
#include <hip/hip_runtime.h>

#define N_NODES 100000
#define N_EDGES 1600000
#define NFEAT 128
#define NHID 64
#define N_GRAPHS 64
#define NLAYER 3
#define BN_EPS 1e-5f
#define POOL_SLICES 8

// ---------------------------------------------------------------- zero misc
__global__ void k_zero(float* __restrict__ stats, float* __restrict__ out,
                       int* __restrict__ deg) {
    int i = blockIdx.x * 256 + threadIdx.x;
    if (i < 4 * 128) stats[i] = 0.f;
    if (i < N_GRAPHS * NHID) out[i] = 0.f;
    if (i < N_NODES) deg[i] = 0;
}

// ------------------------------------------------------------- edge degrees
// (counts[] histogram removed: batch is sorted -> k_offs binary-search.
//  The old fused kernel serialized ~1562 same-address atomics per graph
//  counter = 540 us. deg atomics spread over 100K addresses are cheap.)
__global__ void k_deg(const int* __restrict__ dst, int* __restrict__ deg) {
    int i = blockIdx.x * 256 + threadIdx.x;
    if (i < N_EDGES) {
        int d = dst[i];
        d = max(0, min(N_NODES - 1, d));
        atomicAdd(&deg[d], 1);
    }
}

// ---------------------------------------- graph offsets via binary search
// batch is sorted ascending; offs[t] = lower_bound(batch, t), t in [0,64].
__global__ void k_offs(const int* __restrict__ batch, int* __restrict__ offs) {
    int t = threadIdx.x;
    if (t > N_GRAPHS) return;
    int lo = 0, hi = N_NODES;
    while (lo < hi) {
        int mid = (lo + hi) >> 1;
        if (batch[mid] < t) lo = mid + 1; else hi = mid;
    }
    offs[t] = lo;
}

// ------------------------------------------------------- scan node degrees
__global__ __launch_bounds__(1024) void k_scan_nodes(const int* __restrict__ deg,
                                                     int* __restrict__ row_start,
                                                     int* __restrict__ cursor) {
    __shared__ int part[1024];
    __shared__ int base[1025];
    const int CH = (N_NODES + 1023) / 1024;  // 98
    int t = threadIdx.x;
    int lo = t * CH, hi = min(lo + CH, N_NODES);
    int s = 0;
    for (int i = lo; i < hi; ++i) s += deg[i];
    part[t] = s;
    __syncthreads();
    if (t == 0) {
        int acc = 0;
        base[0] = 0;
        for (int i = 0; i < 1024; ++i) { acc += part[i]; base[i + 1] = acc; }
    }
    __syncthreads();
    int acc = base[t];
    for (int i = lo; i < hi; ++i) {
        row_start[i] = acc;
        cursor[i] = acc;
        acc += deg[i];
    }
    if (t == 1023) row_start[N_NODES] = base[1024];
}

// --------------------------------------------------------------- CSR fill
__global__ void k_fill(const int* __restrict__ src, const int* __restrict__ dst,
                       int* __restrict__ cursor, int* __restrict__ esrc) {
    int e = blockIdx.x * 256 + threadIdx.x;
    if (e < N_EDGES) {
        int d = dst[e];
        d = max(0, min(N_NODES - 1, d));
        int s = src[e];
        s = max(0, min(N_NODES - 1, s));
        int slot = atomicAdd(&cursor[d], 1);
        if (slot >= 0 && slot < N_EDGES) esrc[slot] = s;
    }
}

// ------------------------------------------------------------------- GEMM
// C[M,64] = act(A[M,K] @ W[K,64] + bias), optional relu, optional fused
// column sum/sumsq accumulation into stats[0..63]=sum, stats[64..127]=sumsq.
// block = 256 threads, tile ROWS x 64, per-thread RPT rows x 4 cols.
template <int K, int ROWS, int RPT, bool RELU, bool STATS>
__global__ __launch_bounds__(256) void k_gemm(const float* __restrict__ A,
                                              const float* __restrict__ W,
                                              const float* __restrict__ bias,
                                              float* __restrict__ C,
                                              float* __restrict__ stats, int M) {
    const int ROWP = ROWS + 4;  // pad: conflict-free b128 reads along r
    __shared__ float At[K * ROWP];   // transposed A tile: At[k][r]
    __shared__ float Ws[K * NHID];   // W[k][c]
    __shared__ float sblk[NHID], ssblk[NHID];
    int t = threadIdx.x;
    if (STATS && t < NHID) { sblk[t] = 0.f; ssblk[t] = 0.f; }
    int row0 = blockIdx.x * ROWS;

    // stage W (linear copy, float4)
    for (int i = t; i < K * NHID / 4; i += 256)
        ((float4*)Ws)[i] = ((const float4*)W)[i];

    // stage A transposed
    const int QK = K / 4;
    for (int i = t; i < ROWS * QK; i += 256) {
        int r = i / QK, q = i - r * QK;
        int gr = row0 + r;
        float4 v = make_float4(0.f, 0.f, 0.f, 0.f);
        if (gr < M) v = ((const float4*)(A + (size_t)gr * K))[q];
        At[(4 * q + 0) * ROWP + r] = v.x;
        At[(4 * q + 1) * ROWP + r] = v.y;
        At[(4 * q + 2) * ROWP + r] = v.z;
        At[(4 * q + 3) * ROWP + r] = v.w;
    }
    __syncthreads();

    int c0 = (t & 15) * 4;
    int r0 = (t >> 4) * RPT;
    float acc[RPT][4];
#pragma unroll
    for (int i = 0; i < RPT; ++i) {
        acc[i][0] = 0.f; acc[i][1] = 0.f; acc[i][2] = 0.f; acc[i][3] = 0.f;
    }

#pragma unroll 4
    for (int k = 0; k < K; ++k) {
        float4 w = *(const float4*)&Ws[k * NHID + c0];
#pragma unroll
        for (int ii = 0; ii < RPT / 4; ++ii) {
            float4 a = *(const float4*)&At[k * ROWP + r0 + 4 * ii];
            acc[4 * ii + 0][0] = fmaf(a.x, w.x, acc[4 * ii + 0][0]);
            acc[4 * ii + 0][1] = fmaf(a.x, w.y, acc[4 * ii + 0][1]);
            acc[4 * ii + 0][2] = fmaf(a.x, w.z, acc[4 * ii + 0][2]);
            acc[4 * ii + 0][3] = fmaf(a.x, w.w, acc[4 * ii + 0][3]);
            acc[4 * ii + 1][0] = fmaf(a.y, w.x, acc[4 * ii + 1][0]);
            acc[4 * ii + 1][1] = fmaf(a.y, w.y, acc[4 * ii + 1][1]);
            acc[4 * ii + 1][2] = fmaf(a.y, w.z, acc[4 * ii + 1][2]);
            acc[4 * ii + 1][3] = fmaf(a.y, w.w, acc[4 * ii + 1][3]);
            acc[4 * ii + 2][0] = fmaf(a.z, w.x, acc[4 * ii + 2][0]);
            acc[4 * ii + 2][1] = fmaf(a.z, w.y, acc[4 * ii + 2][1]);
            acc[4 * ii + 2][2] = fmaf(a.z, w.z, acc[4 * ii + 2][2]);
            acc[4 * ii + 2][3] = fmaf(a.z, w.w, acc[4 * ii + 2][3]);
            acc[4 * ii + 3][0] = fmaf(a.w, w.x, acc[4 * ii + 3][0]);
            acc[4 * ii + 3][1] = fmaf(a.w, w.y, acc[4 * ii + 3][1]);
            acc[4 * ii + 3][2] = fmaf(a.w, w.z, acc[4 * ii + 3][2]);
            acc[4 * ii + 3][3] = fmaf(a.w, w.w, acc[4 * ii + 3][3]);
        }
    }

    float4 b4 = *(const float4*)&bias[c0];
    float sp[4] = {0.f, 0.f, 0.f, 0.f};
    float ssp[4] = {0.f, 0.f, 0.f, 0.f};
#pragma unroll
    for (int i = 0; i < RPT; ++i) {
        int gr = row0 + r0 + i;
        if (gr < M) {
            float4 v;
            v.x = acc[i][0] + b4.x;
            v.y = acc[i][1] + b4.y;
            v.z = acc[i][2] + b4.z;
            v.w = acc[i][3] + b4.w;
            if (RELU) {
                v.x = fmaxf(v.x, 0.f); v.y = fmaxf(v.y, 0.f);
                v.z = fmaxf(v.z, 0.f); v.w = fmaxf(v.w, 0.f);
            }
            *(float4*)(C + (size_t)gr * NHID + c0) = v;
            if (STATS) {
                sp[0] += v.x; sp[1] += v.y; sp[2] += v.z; sp[3] += v.w;
                ssp[0] += v.x * v.x; ssp[1] += v.y * v.y;
                ssp[2] += v.z * v.z; ssp[3] += v.w * v.w;
            }
        }
    }

    if (STATS) {
        // lanes l, l+16, l+32, l+48 share the same 4 columns
#pragma unroll
        for (int j = 0; j < 4; ++j) {
            sp[j] += __shfl_down(sp[j], 32);
            sp[j] += __shfl_down(sp[j], 16);
            ssp[j] += __shfl_down(ssp[j], 32);
            ssp[j] += __shfl_down(ssp[j], 16);
        }
        if ((t & 63) < 16) {
#pragma unroll
            for (int j = 0; j < 4; ++j) {
                atomicAdd(&sblk[c0 + j], sp[j]);
                atomicAdd(&ssblk[c0 + j], ssp[j]);
            }
        }
        __syncthreads();
        if (t < NHID) {
            atomicAdd(&stats[t], sblk[t]);
            atomicAdd(&stats[NHID + t], ssblk[t]);
        }
    }
}

// ------------------------------------------------------------ BN normalize
__global__ void k_bn(const float* __restrict__ in, const float* __restrict__ stats,
                     const float* __restrict__ g, const float* __restrict__ b,
                     float* __restrict__ h) {
    int i = blockIdx.x * 256 + threadIdx.x;
    const int n4 = N_NODES * NHID / 4;
    if (i >= n4) return;
    int c4 = i & 15;
    float4 s4 = ((const float4*)stats)[c4];
    float4 q4 = ((const float4*)(stats + NHID))[c4];
    float4 g4 = ((const float4*)g)[c4];
    float4 b4 = ((const float4*)b)[c4];
    const float invN = 1.0f / (float)N_NODES;
    float4 v = ((const float4*)in)[i];
    float4 o;
    {
        float m = s4.x * invN, var = q4.x * invN - m * m;
        o.x = (v.x - m) * rsqrtf(var + BN_EPS) * g4.x + b4.x;
    }
    {
        float m = s4.y * invN, var = q4.y * invN - m * m;
        o.y = (v.y - m) * rsqrtf(var + BN_EPS) * g4.y + b4.y;
    }
    {
        float m = s4.z * invN, var = q4.z * invN - m * m;
        o.z = (v.z - m) * rsqrtf(var + BN_EPS) * g4.z + b4.z;
    }
    {
        float m = s4.w * invN, var = q4.w * invN - m * m;
        o.w = (v.w - m) * rsqrtf(var + BN_EPS) * g4.w + b4.w;
    }
    ((float4*)h)[i] = o;
}

// ------------------------------------------------ gather-based aggregation
// z[i] = h[i] + sum_{e: dst(e)==i} h[src(e)]   (one wave per node, lane=feat)
__global__ __launch_bounds__(256) void k_agg(const float* __restrict__ h,
                                             const int* __restrict__ row_start,
                                             const int* __restrict__ esrc,
                                             float* __restrict__ z) {
    int w = (blockIdx.x * 256 + threadIdx.x) >> 6;
    int l = threadIdx.x & 63;
    if (w >= N_NODES) return;
    int s = row_start[w], e = row_start[w + 1];
    float acc = h[(size_t)w * NHID + l];
    int i = s;
    for (; i + 1 < e; i += 2) {
        int s0 = esrc[i], s1 = esrc[i + 1];
        float a0 = h[(size_t)s0 * NHID + l];
        float a1 = h[(size_t)s1 * NHID + l];
        acc += a0;
        acc += a1;
    }
    if (i < e) acc += h[(size_t)esrc[i] * NHID + l];
    z[(size_t)w * NHID + l] = acc;
}

// ------------------------------------------------------------ mean pooling
// grid = 64 graphs x POOL_SLICES row-slices; accumulates mean into out.
__global__ void k_pool(const float* __restrict__ h, const int* __restrict__ offs,
                       float* __restrict__ out) {
    int g = blockIdx.x & 63;
    int slice = blockIdx.x >> 6;
    int s = offs[g], e = offs[g + 1];
    int f = threadIdx.x & 63, j = threadIdx.x >> 6;
    float acc = 0.f;
    for (int n = s + j + slice * 4; n < e; n += 4 * POOL_SLICES)
        acc += h[(size_t)n * NHID + f];
    __shared__ float red[4][NHID];
    red[j][f] = acc;
    __syncthreads();
    if (threadIdx.x < NHID) {
        float v = red[0][f] + red[1][f] + red[2][f] + red[3][f];
        int cnt = e - s;
        if (cnt > 0) atomicAdd(&out[g * NHID + f], v / (float)cnt);
    }
}

// ------------------------------------------------------------------- host
extern "C" void kernel_launch(void* const* d_in, const int* in_sizes, int n_in,
                              void* d_out, int out_size, void* d_ws, size_t ws_size,
                              hipStream_t stream) {
    const float* x     = (const float*)d_in[0];
    const int*   ei    = (const int*)d_in[1];
    const int*   batch = (const int*)d_in[2];
    const float* W_t   = (const float*)d_in[3];
    const float* b_t   = (const float*)d_in[4];
    const float* bn0_g = (const float*)d_in[5];
    const float* bn0_b = (const float*)d_in[6];
    const float* W1    = (const float*)d_in[7];
    const float* b1    = (const float*)d_in[8];
    const float* W2    = (const float*)d_in[9];
    const float* b2    = (const float*)d_in[10];
    const float* bng   = (const float*)d_in[11];
    const float* bnb   = (const float*)d_in[12];
    float* out = (float*)d_out;

    const size_t NM = (size_t)N_NODES * NHID;
    // workspace layout + size guard (floats then ints)
    const size_t need_bytes =
        (3 * NM + 4 * 128) * sizeof(float) +
        (size_t)((N_GRAPHS + 1) + N_NODES + (N_NODES + 1) + N_NODES + N_EDGES) *
            sizeof(int);
    if (ws_size < need_bytes) return;  // refuse to corrupt memory

    float* buf0  = (float*)d_ws;
    float* buf1  = buf0 + NM;
    float* buf2  = buf1 + NM;
    float* stats = buf2 + NM;                 // 4 stages x 128 floats
    int* offs      = (int*)(stats + 4 * 128); // 65
    int* deg       = offs + N_GRAPHS + 1;     // N
    int* row_start = deg + N_NODES;           // N+1
    int* cursor    = row_start + N_NODES + 1; // N
    int* esrc      = cursor + N_NODES;        // E

    const int* src = ei;
    const int* dst = ei + N_EDGES;

    // --- setup: zero, degrees, offsets, scan, CSR fill ---
    k_zero<<<(N_NODES + 255) / 256, 256, 0, stream>>>(stats, out, deg);
    k_deg<<<(N_EDGES + 255) / 256, 256, 0, stream>>>(dst, deg);
    k_offs<<<1, 128, 0, stream>>>(batch, offs);
    k_scan_nodes<<<1, 1024, 0, stream>>>(deg, row_start, cursor);
    k_fill<<<(N_EDGES + 255) / 256, 256, 0, stream>>>(src, dst, cursor, esrc);

    // --- transform: h0 = BN(x @ W_t + b_t) ---
    k_gemm<NFEAT, 64, 4, false, true>
        <<<(N_NODES + 63) / 64, 256, 0, stream>>>(x, W_t, b_t, buf0, stats, N_NODES);
    k_bn<<<(int)(NM / 4 + 255) / 256, 256, 0, stream>>>(buf0, stats, bn0_g, bn0_b, buf1);
    k_pool<<<64 * POOL_SLICES, 256, 0, stream>>>(buf1, offs, out);

    // --- GIN layers ---
    float* A = buf1;   // h
    float* B = buf2;   // scratch
    float* Cb = buf0;  // scratch
    for (int i = 0; i < NLAYER; ++i) {
        k_agg<<<(N_NODES * 64 + 255) / 256, 256, 0, stream>>>(A, row_start, esrc, B);
        k_gemm<NHID, 128, 8, true, false>
            <<<(N_NODES + 127) / 128, 256, 0, stream>>>(B, W1 + i * NHID * NHID,
                                                        b1 + i * NHID, Cb, nullptr, N_NODES);
        k_gemm<NHID, 128, 8, true, true>
            <<<(N_NODES + 127) / 128, 256, 0, stream>>>(Cb, W2 + i * NHID * NHID,
                                                        b2 + i * NHID, B,
                                                        stats + (1 + i) * 128, N_NODES);
        k_bn<<<(int)(NM / 4 + 255) / 256, 256, 0, stream>>>(B, stats + (1 + i) * 128,
                                                            bng + i * NHID, bnb + i * NHID, Cb);
        k_pool<<<64 * POOL_SLICES, 256, 0, stream>>>(Cb, offs, out);
        // rotate: h now in Cb
        float* tmp = A;
        A = Cb;
        Cb = B;
        B = tmp;
    }
}

// Round 6
// 913.688 us; speedup vs baseline: 1.7966x; 1.2645x over previous
//
#include <hip/hip_runtime.h>

#define N_NODES 100000
#define N_EDGES 1600000
#define NFEAT 128
#define NHID 64
#define N_GRAPHS 64
#define NLAYER 3
#define BN_EPS 1e-5f
#define POOL_SLICES 8
#define SCAN_BLOCKS ((N_NODES + 1023) / 1024)  // 98

// ---------------------------------------------------------------- zero misc
__global__ void k_zero(float* __restrict__ stats, float* __restrict__ out,
                       int* __restrict__ deg) {
    int i = blockIdx.x * 256 + threadIdx.x;
    if (i < 4 * 128) stats[i] = 0.f;
    if (i < N_GRAPHS * NHID) out[i] = 0.f;
    if (i < N_NODES) deg[i] = 0;
}

// ------------------------------------------------------------- edge degrees
__global__ void k_deg(const int* __restrict__ dst, int* __restrict__ deg) {
    int i = blockIdx.x * 256 + threadIdx.x;
    if (i < N_EDGES) {
        int d = dst[i];
        d = max(0, min(N_NODES - 1, d));
        atomicAdd(&deg[d], 1);
    }
}

// ---------------------------------------- graph offsets via binary search
// batch is sorted ascending; offs[t] = lower_bound(batch, t), t in [0,64].
__global__ void k_offs(const int* __restrict__ batch, int* __restrict__ offs) {
    int t = threadIdx.x;
    if (t > N_GRAPHS) return;
    int lo = 0, hi = N_NODES;
    while (lo < hi) {
        int mid = (lo + hi) >> 1;
        if (batch[mid] < t) lo = mid + 1; else hi = mid;
    }
    offs[t] = lo;
}

// ------------------------------------------------- hierarchical scan: phase 1
// (replaces single-block k_scan_nodes: 242us at 0.15% occupancy, latency-bound)
__global__ __launch_bounds__(1024) void k_scan_partial(const int* __restrict__ deg,
                                                       int* __restrict__ part) {
    int t = threadIdx.x;
    int i = blockIdx.x * 1024 + t;
    int v = (i < N_NODES) ? deg[i] : 0;
    for (int off = 32; off > 0; off >>= 1) v += __shfl_down(v, off);
    __shared__ int ws[16];
    if ((t & 63) == 0) ws[t >> 6] = v;
    __syncthreads();
    if (t == 0) {
        int s = 0;
#pragma unroll
        for (int k = 0; k < 16; ++k) s += ws[k];
        part[blockIdx.x] = s;
    }
}

// ------------------------------------------------- hierarchical scan: phase 2
__global__ void k_scan_base(int* __restrict__ part) {
    __shared__ int s[128];
    int t = threadIdx.x;
    s[t] = (t < SCAN_BLOCKS) ? part[t] : 0;
    __syncthreads();
    if (t == 0) {
        int acc = 0;
        for (int i = 0; i < SCAN_BLOCKS; ++i) { int p = s[i]; s[i] = acc; acc += p; }
    }
    __syncthreads();
    if (t < SCAN_BLOCKS) part[t] = s[t];
}

// ------------------------------------------------- hierarchical scan: phase 3
__global__ __launch_bounds__(1024) void k_scan_final(const int* __restrict__ deg,
                                                     const int* __restrict__ part,
                                                     int* __restrict__ row_start,
                                                     int* __restrict__ cursor) {
    int t = threadIdx.x;
    int i = blockIdx.x * 1024 + t;
    int v = (i < N_NODES) ? deg[i] : 0;
    int lane = t & 63;
    // inclusive wave scan
    int incl = v;
    for (int off = 1; off < 64; off <<= 1) {
        int n = __shfl_up(incl, off);
        if (lane >= off) incl += n;
    }
    __shared__ int wsum[16];
    int w = t >> 6;
    if (lane == 63) wsum[w] = incl;
    __syncthreads();
    if (t < 16) {
        int s = wsum[t];
        int e = s;
        for (int off = 1; off < 16; off <<= 1) {
            int n = __shfl_up(e, off, 16);
            if (t >= off) e += n;
        }
        wsum[t] = e - s;  // exclusive wave base
    }
    __syncthreads();
    int excl = incl - v + wsum[w] + part[blockIdx.x];
    if (i < N_NODES) {
        row_start[i] = excl;
        cursor[i] = excl;
        if (i == N_NODES - 1) row_start[N_NODES] = excl + v;
    }
}

// --------------------------------------------------------------- CSR fill
__global__ void k_fill(const int* __restrict__ src, const int* __restrict__ dst,
                       int* __restrict__ cursor, int* __restrict__ esrc) {
    int e = blockIdx.x * 256 + threadIdx.x;
    if (e < N_EDGES) {
        int d = dst[e];
        d = max(0, min(N_NODES - 1, d));
        int s = src[e];
        s = max(0, min(N_NODES - 1, s));
        int slot = atomicAdd(&cursor[d], 1);
        if (slot >= 0 && slot < N_EDGES) esrc[slot] = s;
    }
}

// ------------------------------------------------------------------- GEMM
// C[M,64] = act(A[M,K] @ W[K,64] + bias), optional relu, optional fused
// column sum/sumsq accumulation into stats[0..63]=sum, stats[64..127]=sumsq.
template <int K, int ROWS, int RPT, bool RELU, bool STATS>
__global__ __launch_bounds__(256) void k_gemm(const float* __restrict__ A,
                                              const float* __restrict__ W,
                                              const float* __restrict__ bias,
                                              float* __restrict__ C,
                                              float* __restrict__ stats, int M) {
    const int ROWP = ROWS + 4;  // pad: conflict-free b128 reads along r
    __shared__ float At[K * ROWP];   // transposed A tile: At[k][r]
    __shared__ float Ws[K * NHID];   // W[k][c]
    __shared__ float sblk[NHID], ssblk[NHID];
    int t = threadIdx.x;
    if (STATS && t < NHID) { sblk[t] = 0.f; ssblk[t] = 0.f; }
    int row0 = blockIdx.x * ROWS;

    // stage W (linear copy, float4)
    for (int i = t; i < K * NHID / 4; i += 256)
        ((float4*)Ws)[i] = ((const float4*)W)[i];

    // stage A transposed
    const int QK = K / 4;
    for (int i = t; i < ROWS * QK; i += 256) {
        int r = i / QK, q = i - r * QK;
        int gr = row0 + r;
        float4 v = make_float4(0.f, 0.f, 0.f, 0.f);
        if (gr < M) v = ((const float4*)(A + (size_t)gr * K))[q];
        At[(4 * q + 0) * ROWP + r] = v.x;
        At[(4 * q + 1) * ROWP + r] = v.y;
        At[(4 * q + 2) * ROWP + r] = v.z;
        At[(4 * q + 3) * ROWP + r] = v.w;
    }
    __syncthreads();

    int c0 = (t & 15) * 4;
    int r0 = (t >> 4) * RPT;
    float acc[RPT][4];
#pragma unroll
    for (int i = 0; i < RPT; ++i) {
        acc[i][0] = 0.f; acc[i][1] = 0.f; acc[i][2] = 0.f; acc[i][3] = 0.f;
    }

#pragma unroll 4
    for (int k = 0; k < K; ++k) {
        float4 w = *(const float4*)&Ws[k * NHID + c0];
#pragma unroll
        for (int ii = 0; ii < RPT / 4; ++ii) {
            float4 a = *(const float4*)&At[k * ROWP + r0 + 4 * ii];
            acc[4 * ii + 0][0] = fmaf(a.x, w.x, acc[4 * ii + 0][0]);
            acc[4 * ii + 0][1] = fmaf(a.x, w.y, acc[4 * ii + 0][1]);
            acc[4 * ii + 0][2] = fmaf(a.x, w.z, acc[4 * ii + 0][2]);
            acc[4 * ii + 0][3] = fmaf(a.x, w.w, acc[4 * ii + 0][3]);
            acc[4 * ii + 1][0] = fmaf(a.y, w.x, acc[4 * ii + 1][0]);
            acc[4 * ii + 1][1] = fmaf(a.y, w.y, acc[4 * ii + 1][1]);
            acc[4 * ii + 1][2] = fmaf(a.y, w.z, acc[4 * ii + 1][2]);
            acc[4 * ii + 1][3] = fmaf(a.y, w.w, acc[4 * ii + 1][3]);
            acc[4 * ii + 2][0] = fmaf(a.z, w.x, acc[4 * ii + 2][0]);
            acc[4 * ii + 2][1] = fmaf(a.z, w.y, acc[4 * ii + 2][1]);
            acc[4 * ii + 2][2] = fmaf(a.z, w.z, acc[4 * ii + 2][2]);
            acc[4 * ii + 2][3] = fmaf(a.z, w.w, acc[4 * ii + 2][3]);
            acc[4 * ii + 3][0] = fmaf(a.w, w.x, acc[4 * ii + 3][0]);
            acc[4 * ii + 3][1] = fmaf(a.w, w.y, acc[4 * ii + 3][1]);
            acc[4 * ii + 3][2] = fmaf(a.w, w.z, acc[4 * ii + 3][2]);
            acc[4 * ii + 3][3] = fmaf(a.w, w.w, acc[4 * ii + 3][3]);
        }
    }

    float4 b4 = *(const float4*)&bias[c0];
    float sp[4] = {0.f, 0.f, 0.f, 0.f};
    float ssp[4] = {0.f, 0.f, 0.f, 0.f};
#pragma unroll
    for (int i = 0; i < RPT; ++i) {
        int gr = row0 + r0 + i;
        if (gr < M) {
            float4 v;
            v.x = acc[i][0] + b4.x;
            v.y = acc[i][1] + b4.y;
            v.z = acc[i][2] + b4.z;
            v.w = acc[i][3] + b4.w;
            if (RELU) {
                v.x = fmaxf(v.x, 0.f); v.y = fmaxf(v.y, 0.f);
                v.z = fmaxf(v.z, 0.f); v.w = fmaxf(v.w, 0.f);
            }
            *(float4*)(C + (size_t)gr * NHID + c0) = v;
            if (STATS) {
                sp[0] += v.x; sp[1] += v.y; sp[2] += v.z; sp[3] += v.w;
                ssp[0] += v.x * v.x; ssp[1] += v.y * v.y;
                ssp[2] += v.z * v.z; ssp[3] += v.w * v.w;
            }
        }
    }

    if (STATS) {
        // lanes l, l+16, l+32, l+48 share the same 4 columns
#pragma unroll
        for (int j = 0; j < 4; ++j) {
            sp[j] += __shfl_down(sp[j], 32);
            sp[j] += __shfl_down(sp[j], 16);
            ssp[j] += __shfl_down(ssp[j], 32);
            ssp[j] += __shfl_down(ssp[j], 16);
        }
        if ((t & 63) < 16) {
#pragma unroll
            for (int j = 0; j < 4; ++j) {
                atomicAdd(&sblk[c0 + j], sp[j]);
                atomicAdd(&ssblk[c0 + j], ssp[j]);
            }
        }
        __syncthreads();
        if (t < NHID) {
            atomicAdd(&stats[t], sblk[t]);
            atomicAdd(&stats[NHID + t], ssblk[t]);
        }
    }
}

// ------------------------------------------------------------ BN normalize
__global__ void k_bn(const float* __restrict__ in, const float* __restrict__ stats,
                     const float* __restrict__ g, const float* __restrict__ b,
                     float* __restrict__ h) {
    int i = blockIdx.x * 256 + threadIdx.x;
    const int n4 = N_NODES * NHID / 4;
    if (i >= n4) return;
    int c4 = i & 15;
    float4 s4 = ((const float4*)stats)[c4];
    float4 q4 = ((const float4*)(stats + NHID))[c4];
    float4 g4 = ((const float4*)g)[c4];
    float4 b4 = ((const float4*)b)[c4];
    const float invN = 1.0f / (float)N_NODES;
    float4 v = ((const float4*)in)[i];
    float4 o;
    {
        float m = s4.x * invN, var = q4.x * invN - m * m;
        o.x = (v.x - m) * rsqrtf(var + BN_EPS) * g4.x + b4.x;
    }
    {
        float m = s4.y * invN, var = q4.y * invN - m * m;
        o.y = (v.y - m) * rsqrtf(var + BN_EPS) * g4.y + b4.y;
    }
    {
        float m = s4.z * invN, var = q4.z * invN - m * m;
        o.z = (v.z - m) * rsqrtf(var + BN_EPS) * g4.z + b4.z;
    }
    {
        float m = s4.w * invN, var = q4.w * invN - m * m;
        o.w = (v.w - m) * rsqrtf(var + BN_EPS) * g4.w + b4.w;
    }
    ((float4*)h)[i] = o;
}

// ------------------------------------------------ gather-based aggregation
// z[i] = h[i] + sum_{e: dst(e)==i} h[src(e)]   (one wave per node, lane=feat)
__global__ __launch_bounds__(256) void k_agg(const float* __restrict__ h,
                                             const int* __restrict__ row_start,
                                             const int* __restrict__ esrc,
                                             float* __restrict__ z) {
    int w = (blockIdx.x * 256 + threadIdx.x) >> 6;
    int l = threadIdx.x & 63;
    if (w >= N_NODES) return;
    int s = row_start[w], e = row_start[w + 1];
    float acc = h[(size_t)w * NHID + l];
    int i = s;
    for (; i + 1 < e; i += 2) {
        int s0 = esrc[i], s1 = esrc[i + 1];
        float a0 = h[(size_t)s0 * NHID + l];
        float a1 = h[(size_t)s1 * NHID + l];
        acc += a0;
        acc += a1;
    }
    if (i < e) acc += h[(size_t)esrc[i] * NHID + l];
    z[(size_t)w * NHID + l] = acc;
}

// ------------------------------------------------------------ mean pooling
// grid = 64 graphs x POOL_SLICES row-slices; accumulates mean into out.
__global__ void k_pool(const float* __restrict__ h, const int* __restrict__ offs,
                       float* __restrict__ out) {
    int g = blockIdx.x & 63;
    int slice = blockIdx.x >> 6;
    int s = offs[g], e = offs[g + 1];
    int f = threadIdx.x & 63, j = threadIdx.x >> 6;
    float acc = 0.f;
    for (int n = s + j + slice * 4; n < e; n += 4 * POOL_SLICES)
        acc += h[(size_t)n * NHID + f];
    __shared__ float red[4][NHID];
    red[j][f] = acc;
    __syncthreads();
    if (threadIdx.x < NHID) {
        float v = red[0][f] + red[1][f] + red[2][f] + red[3][f];
        int cnt = e - s;
        if (cnt > 0) atomicAdd(&out[g * NHID + f], v / (float)cnt);
    }
}

// ------------------------------------------------------------------- host
extern "C" void kernel_launch(void* const* d_in, const int* in_sizes, int n_in,
                              void* d_out, int out_size, void* d_ws, size_t ws_size,
                              hipStream_t stream) {
    const float* x     = (const float*)d_in[0];
    const int*   ei    = (const int*)d_in[1];
    const int*   batch = (const int*)d_in[2];
    const float* W_t   = (const float*)d_in[3];
    const float* b_t   = (const float*)d_in[4];
    const float* bn0_g = (const float*)d_in[5];
    const float* bn0_b = (const float*)d_in[6];
    const float* W1    = (const float*)d_in[7];
    const float* b1    = (const float*)d_in[8];
    const float* W2    = (const float*)d_in[9];
    const float* b2    = (const float*)d_in[10];
    const float* bng   = (const float*)d_in[11];
    const float* bnb   = (const float*)d_in[12];
    float* out = (float*)d_out;

    const size_t NM = (size_t)N_NODES * NHID;
    // workspace layout + size guard (floats then ints)
    const size_t need_bytes =
        (3 * NM + 4 * 128) * sizeof(float) +
        (size_t)((N_GRAPHS + 1) + N_NODES + (N_NODES + 1) + N_NODES + N_EDGES +
                 SCAN_BLOCKS) * sizeof(int);
    if (ws_size < need_bytes) return;  // refuse to corrupt memory

    float* buf0  = (float*)d_ws;
    float* buf1  = buf0 + NM;
    float* buf2  = buf1 + NM;
    float* stats = buf2 + NM;                 // 4 stages x 128 floats
    int* offs      = (int*)(stats + 4 * 128); // 65
    int* deg       = offs + N_GRAPHS + 1;     // N
    int* row_start = deg + N_NODES;           // N+1
    int* cursor    = row_start + N_NODES + 1; // N
    int* esrc      = cursor + N_NODES;        // E
    int* part      = esrc + N_EDGES;          // SCAN_BLOCKS

    const int* src = ei;
    const int* dst = ei + N_EDGES;

    // --- setup: zero, degrees, offsets, hierarchical scan, CSR fill ---
    k_zero<<<(N_NODES + 255) / 256, 256, 0, stream>>>(stats, out, deg);
    k_deg<<<(N_EDGES + 255) / 256, 256, 0, stream>>>(dst, deg);
    k_offs<<<1, 128, 0, stream>>>(batch, offs);
    k_scan_partial<<<SCAN_BLOCKS, 1024, 0, stream>>>(deg, part);
    k_scan_base<<<1, 128, 0, stream>>>(part);
    k_scan_final<<<SCAN_BLOCKS, 1024, 0, stream>>>(deg, part, row_start, cursor);
    k_fill<<<(N_EDGES + 255) / 256, 256, 0, stream>>>(src, dst, cursor, esrc);

    // --- transform: h0 = BN(x @ W_t + b_t) ---
    k_gemm<NFEAT, 64, 4, false, true>
        <<<(N_NODES + 63) / 64, 256, 0, stream>>>(x, W_t, b_t, buf0, stats, N_NODES);
    k_bn<<<(int)(NM / 4 + 255) / 256, 256, 0, stream>>>(buf0, stats, bn0_g, bn0_b, buf1);
    k_pool<<<64 * POOL_SLICES, 256, 0, stream>>>(buf1, offs, out);

    // --- GIN layers ---
    float* A = buf1;   // h
    float* B = buf2;   // scratch
    float* Cb = buf0;  // scratch
    for (int i = 0; i < NLAYER; ++i) {
        k_agg<<<(N_NODES * 64 + 255) / 256, 256, 0, stream>>>(A, row_start, esrc, B);
        k_gemm<NHID, 128, 8, true, false>
            <<<(N_NODES + 127) / 128, 256, 0, stream>>>(B, W1 + i * NHID * NHID,
                                                        b1 + i * NHID, Cb, nullptr, N_NODES);
        k_gemm<NHID, 128, 8, true, true>
            <<<(N_NODES + 127) / 128, 256, 0, stream>>>(Cb, W2 + i * NHID * NHID,
                                                        b2 + i * NHID, B,
                                                        stats + (1 + i) * 128, N_NODES);
        k_bn<<<(int)(NM / 4 + 255) / 256, 256, 0, stream>>>(B, stats + (1 + i) * 128,
                                                            bng + i * NHID, bnb + i * NHID, Cb);
        k_pool<<<64 * POOL_SLICES, 256, 0, stream>>>(Cb, offs, out);
        // rotate: h now in Cb
        float* tmp = A;
        A = Cb;
        Cb = B;
        B = tmp;
    }
}

// Round 7
// 749.483 us; speedup vs baseline: 2.1902x; 1.2191x over previous
//
#include <hip/hip_runtime.h>
#include <hip/hip_fp16.h>

#define N_NODES 100000
#define N_EDGES 1600000
#define NFEAT 128
#define NHID 64
#define N_GRAPHS 64
#define NLAYER 3
#define BN_EPS 1e-5f
#define POOL_SLICES 8
#define SCAN_BLOCKS ((N_NODES + 1023) / 1024)  // 98

// ---------------------------------------------------------------- zero misc
__global__ void k_zero(float* __restrict__ stats, float* __restrict__ out,
                       int* __restrict__ deg) {
    int i = blockIdx.x * 256 + threadIdx.x;
    if (i < 4 * 128) stats[i] = 0.f;
    if (i < N_GRAPHS * NHID) out[i] = 0.f;
    if (i < N_NODES) deg[i] = 0;
}

// ------------------------------------------------------------- edge degrees
__global__ void k_deg(const int* __restrict__ dst, int* __restrict__ deg) {
    int i = blockIdx.x * 256 + threadIdx.x;
    if (i < N_EDGES) {
        int d = dst[i];
        d = max(0, min(N_NODES - 1, d));
        atomicAdd(&deg[d], 1);
    }
}

// ---------------------------------------- graph offsets via binary search
__global__ void k_offs(const int* __restrict__ batch, int* __restrict__ offs) {
    int t = threadIdx.x;
    if (t > N_GRAPHS) return;
    int lo = 0, hi = N_NODES;
    while (lo < hi) {
        int mid = (lo + hi) >> 1;
        if (batch[mid] < t) lo = mid + 1; else hi = mid;
    }
    offs[t] = lo;
}

// ------------------------------------------------- hierarchical scan: phase 1
__global__ __launch_bounds__(1024) void k_scan_partial(const int* __restrict__ deg,
                                                       int* __restrict__ part) {
    int t = threadIdx.x;
    int i = blockIdx.x * 1024 + t;
    int v = (i < N_NODES) ? deg[i] : 0;
    for (int off = 32; off > 0; off >>= 1) v += __shfl_down(v, off);
    __shared__ int ws[16];
    if ((t & 63) == 0) ws[t >> 6] = v;
    __syncthreads();
    if (t == 0) {
        int s = 0;
#pragma unroll
        for (int k = 0; k < 16; ++k) s += ws[k];
        part[blockIdx.x] = s;
    }
}

// ------------------------------------------------- hierarchical scan: phase 2
__global__ void k_scan_base(int* __restrict__ part) {
    __shared__ int s[128];
    int t = threadIdx.x;
    s[t] = (t < SCAN_BLOCKS) ? part[t] : 0;
    __syncthreads();
    if (t == 0) {
        int acc = 0;
        for (int i = 0; i < SCAN_BLOCKS; ++i) { int p = s[i]; s[i] = acc; acc += p; }
    }
    __syncthreads();
    if (t < SCAN_BLOCKS) part[t] = s[t];
}

// ------------------------------------------------- hierarchical scan: phase 3
__global__ __launch_bounds__(1024) void k_scan_final(const int* __restrict__ deg,
                                                     const int* __restrict__ part,
                                                     int* __restrict__ row_start,
                                                     int* __restrict__ cursor) {
    int t = threadIdx.x;
    int i = blockIdx.x * 1024 + t;
    int v = (i < N_NODES) ? deg[i] : 0;
    int lane = t & 63;
    int incl = v;
    for (int off = 1; off < 64; off <<= 1) {
        int n = __shfl_up(incl, off);
        if (lane >= off) incl += n;
    }
    __shared__ int wsum[16];
    int w = t >> 6;
    if (lane == 63) wsum[w] = incl;
    __syncthreads();
    if (t < 16) {
        int s = wsum[t];
        int e = s;
        for (int off = 1; off < 16; off <<= 1) {
            int n = __shfl_up(e, off, 16);
            if (t >= off) e += n;
        }
        wsum[t] = e - s;
    }
    __syncthreads();
    int excl = incl - v + wsum[w] + part[blockIdx.x];
    if (i < N_NODES) {
        row_start[i] = excl;
        cursor[i] = excl;
        if (i == N_NODES - 1) row_start[N_NODES] = excl + v;
    }
}

// --------------------------------------------------------------- CSR fill
__global__ void k_fill(const int* __restrict__ src, const int* __restrict__ dst,
                       int* __restrict__ cursor, int* __restrict__ esrc) {
    int e = blockIdx.x * 256 + threadIdx.x;
    if (e < N_EDGES) {
        int d = dst[e];
        d = max(0, min(N_NODES - 1, d));
        int s = src[e];
        s = max(0, min(N_NODES - 1, s));
        int slot = atomicAdd(&cursor[d], 1);
        if (slot >= 0 && slot < N_EDGES) esrc[slot] = s;
    }
}

// ------------------------------------------------------------------- GEMM
// C[M,64] = act(A[M,K] @ W[K,64] + bias); optional relu; optional fused
// column sum/sumsq into stats; optional fp16 output (pre-BN activations y).
template <int K, int ROWS, int RPT, bool RELU, bool STATS, bool HALF_OUT>
__global__ __launch_bounds__(256) void k_gemm(const float* __restrict__ A,
                                              const float* __restrict__ W,
                                              const float* __restrict__ bias,
                                              void* __restrict__ Cout,
                                              float* __restrict__ stats, int M) {
    const int ROWP = ROWS + 4;
    __shared__ float At[K * ROWP];   // transposed A tile: At[k][r]
    __shared__ float Ws[K * NHID];
    __shared__ float sblk[NHID], ssblk[NHID];
    int t = threadIdx.x;
    if (STATS && t < NHID) { sblk[t] = 0.f; ssblk[t] = 0.f; }
    int row0 = blockIdx.x * ROWS;

    for (int i = t; i < K * NHID / 4; i += 256)
        ((float4*)Ws)[i] = ((const float4*)W)[i];

    const int QK = K / 4;
    for (int i = t; i < ROWS * QK; i += 256) {
        int r = i / QK, q = i - r * QK;
        int gr = row0 + r;
        float4 v = make_float4(0.f, 0.f, 0.f, 0.f);
        if (gr < M) v = ((const float4*)(A + (size_t)gr * K))[q];
        At[(4 * q + 0) * ROWP + r] = v.x;
        At[(4 * q + 1) * ROWP + r] = v.y;
        At[(4 * q + 2) * ROWP + r] = v.z;
        At[(4 * q + 3) * ROWP + r] = v.w;
    }
    __syncthreads();

    int c0 = (t & 15) * 4;
    int r0 = (t >> 4) * RPT;
    float acc[RPT][4];
#pragma unroll
    for (int i = 0; i < RPT; ++i) {
        acc[i][0] = 0.f; acc[i][1] = 0.f; acc[i][2] = 0.f; acc[i][3] = 0.f;
    }

#pragma unroll 4
    for (int k = 0; k < K; ++k) {
        float4 w = *(const float4*)&Ws[k * NHID + c0];
#pragma unroll
        for (int ii = 0; ii < RPT / 4; ++ii) {
            float4 a = *(const float4*)&At[k * ROWP + r0 + 4 * ii];
            acc[4 * ii + 0][0] = fmaf(a.x, w.x, acc[4 * ii + 0][0]);
            acc[4 * ii + 0][1] = fmaf(a.x, w.y, acc[4 * ii + 0][1]);
            acc[4 * ii + 0][2] = fmaf(a.x, w.z, acc[4 * ii + 0][2]);
            acc[4 * ii + 0][3] = fmaf(a.x, w.w, acc[4 * ii + 0][3]);
            acc[4 * ii + 1][0] = fmaf(a.y, w.x, acc[4 * ii + 1][0]);
            acc[4 * ii + 1][1] = fmaf(a.y, w.y, acc[4 * ii + 1][1]);
            acc[4 * ii + 1][2] = fmaf(a.y, w.z, acc[4 * ii + 1][2]);
            acc[4 * ii + 1][3] = fmaf(a.y, w.w, acc[4 * ii + 1][3]);
            acc[4 * ii + 2][0] = fmaf(a.z, w.x, acc[4 * ii + 2][0]);
            acc[4 * ii + 2][1] = fmaf(a.z, w.y, acc[4 * ii + 2][1]);
            acc[4 * ii + 2][2] = fmaf(a.z, w.z, acc[4 * ii + 2][2]);
            acc[4 * ii + 2][3] = fmaf(a.z, w.w, acc[4 * ii + 2][3]);
            acc[4 * ii + 3][0] = fmaf(a.w, w.x, acc[4 * ii + 3][0]);
            acc[4 * ii + 3][1] = fmaf(a.w, w.y, acc[4 * ii + 3][1]);
            acc[4 * ii + 3][2] = fmaf(a.w, w.z, acc[4 * ii + 3][2]);
            acc[4 * ii + 3][3] = fmaf(a.w, w.w, acc[4 * ii + 3][3]);
        }
    }

    float4 b4 = *(const float4*)&bias[c0];
    float sp[4] = {0.f, 0.f, 0.f, 0.f};
    float ssp[4] = {0.f, 0.f, 0.f, 0.f};
#pragma unroll
    for (int i = 0; i < RPT; ++i) {
        int gr = row0 + r0 + i;
        if (gr < M) {
            float4 v;
            v.x = acc[i][0] + b4.x;
            v.y = acc[i][1] + b4.y;
            v.z = acc[i][2] + b4.z;
            v.w = acc[i][3] + b4.w;
            if (RELU) {
                v.x = fmaxf(v.x, 0.f); v.y = fmaxf(v.y, 0.f);
                v.z = fmaxf(v.z, 0.f); v.w = fmaxf(v.w, 0.f);
            }
            if (HALF_OUT) {
                __half2* dst = (__half2*)((__half*)Cout + (size_t)gr * NHID + c0);
                dst[0] = __floats2half2_rn(v.x, v.y);
                dst[1] = __floats2half2_rn(v.z, v.w);
            } else {
                *(float4*)((float*)Cout + (size_t)gr * NHID + c0) = v;
            }
            if (STATS) {
                sp[0] += v.x; sp[1] += v.y; sp[2] += v.z; sp[3] += v.w;
                ssp[0] += v.x * v.x; ssp[1] += v.y * v.y;
                ssp[2] += v.z * v.z; ssp[3] += v.w * v.w;
            }
        }
    }

    if (STATS) {
#pragma unroll
        for (int j = 0; j < 4; ++j) {
            sp[j] += __shfl_down(sp[j], 32);
            sp[j] += __shfl_down(sp[j], 16);
            ssp[j] += __shfl_down(ssp[j], 32);
            ssp[j] += __shfl_down(ssp[j], 16);
        }
        if ((t & 63) < 16) {
#pragma unroll
            for (int j = 0; j < 4; ++j) {
                atomicAdd(&sblk[c0 + j], sp[j]);
                atomicAdd(&ssblk[c0 + j], ssp[j]);
            }
        }
        __syncthreads();
        if (t < NHID) {
            atomicAdd(&stats[t], sblk[t]);
            atomicAdd(&stats[NHID + t], ssblk[t]);
        }
    }
}

// --------------------------------------------- aggregation with folded BN
// z_i = a ∘ (y_i + Σ_{j∈N(i)} y_j) + (1+deg_i)·c,  a/c from BN stats.
// 2 nodes per wave: 32 lanes × half2 (features 2l, 2l+1).
__global__ __launch_bounds__(256) void k_agg(const __half* __restrict__ y,
                                             const int* __restrict__ row_start,
                                             const int* __restrict__ esrc,
                                             const float* __restrict__ stats,
                                             const float* __restrict__ gamma,
                                             const float* __restrict__ beta,
                                             float* __restrict__ z) {
    int w = (blockIdx.x * 256 + threadIdx.x) >> 5;
    int l = threadIdx.x & 31;
    if (w >= N_NODES) return;
    const float invN = 1.0f / (float)N_NODES;
    float m0 = stats[2 * l] * invN,     q0 = stats[NHID + 2 * l] * invN;
    float m1 = stats[2 * l + 1] * invN, q1 = stats[NHID + 2 * l + 1] * invN;
    float i0 = rsqrtf(q0 - m0 * m0 + BN_EPS);
    float i1 = rsqrtf(q1 - m1 * m1 + BN_EPS);
    float g0 = gamma[2 * l], g1 = gamma[2 * l + 1];
    float a0 = g0 * i0, a1 = g1 * i1;
    float c0 = beta[2 * l] - g0 * m0 * i0;
    float c1 = beta[2 * l + 1] - g1 * m1 * i1;

    int s = row_start[w], e = row_start[w + 1];
    float2 acc = __half22float2(((const __half2*)(y + (size_t)w * NHID))[l]);
    int i = s;
    for (; i + 1 < e; i += 2) {
        int s0 = esrc[i], s1 = esrc[i + 1];
        float2 v0 = __half22float2(((const __half2*)(y + (size_t)s0 * NHID))[l]);
        float2 v1 = __half22float2(((const __half2*)(y + (size_t)s1 * NHID))[l]);
        acc.x += v0.x; acc.y += v0.y;
        acc.x += v1.x; acc.y += v1.y;
    }
    if (i < e) {
        float2 v = __half22float2(((const __half2*)(y + (size_t)esrc[i] * NHID))[l]);
        acc.x += v.x; acc.y += v.y;
    }
    float k = (float)(1 + e - s);
    float2 zo;
    zo.x = fmaf(a0, acc.x, k * c0);
    zo.y = fmaf(a1, acc.y, k * c1);
    *(float2*)(z + (size_t)w * NHID + 2 * l) = zo;
}

// -------------------------------------- mean pooling with folded BN affine
// out[g] += a ∘ mean_g(y) + c   (c added by slice 0 only)
__global__ void k_pool(const __half* __restrict__ y, const int* __restrict__ offs,
                       const float* __restrict__ stats,
                       const float* __restrict__ gamma,
                       const float* __restrict__ beta,
                       float* __restrict__ out) {
    int g = blockIdx.x & 63;
    int slice = blockIdx.x >> 6;
    int s = offs[g], e = offs[g + 1];
    int f = threadIdx.x & 31;   // feature pair
    int j = threadIdx.x >> 5;   // 8 node-lanes
    float2 acc = make_float2(0.f, 0.f);
    for (int n = s + j + slice * 8; n < e; n += 8 * POOL_SLICES) {
        float2 v = __half22float2(((const __half2*)(y + (size_t)n * NHID))[f]);
        acc.x += v.x; acc.y += v.y;
    }
    __shared__ float2 red[8][32];
    red[j][f] = acc;
    __syncthreads();
    if (threadIdx.x < 32) {
        float2 t = make_float2(0.f, 0.f);
#pragma unroll
        for (int r = 0; r < 8; ++r) { t.x += red[r][f].x; t.y += red[r][f].y; }
        int cnt = e - s;
        if (cnt > 0) {
            const float invN = 1.0f / (float)N_NODES;
            float m0 = stats[2 * f] * invN,     q0 = stats[NHID + 2 * f] * invN;
            float m1 = stats[2 * f + 1] * invN, q1 = stats[NHID + 2 * f + 1] * invN;
            float i0 = rsqrtf(q0 - m0 * m0 + BN_EPS);
            float i1 = rsqrtf(q1 - m1 * m1 + BN_EPS);
            float g0 = gamma[2 * f], g1 = gamma[2 * f + 1];
            float a0 = g0 * i0, a1 = g1 * i1;
            float c0 = beta[2 * f] - g0 * m0 * i0;
            float c1 = beta[2 * f + 1] - g1 * m1 * i1;
            float inv = 1.0f / (float)cnt;
            float add0 = a0 * t.x * inv + (slice == 0 ? c0 : 0.f);
            float add1 = a1 * t.y * inv + (slice == 0 ? c1 : 0.f);
            atomicAdd(&out[g * NHID + 2 * f], add0);
            atomicAdd(&out[g * NHID + 2 * f + 1], add1);
        }
    }
}

// ------------------------------------------------------------------- host
extern "C" void kernel_launch(void* const* d_in, const int* in_sizes, int n_in,
                              void* d_out, int out_size, void* d_ws, size_t ws_size,
                              hipStream_t stream) {
    const float* x     = (const float*)d_in[0];
    const int*   ei    = (const int*)d_in[1];
    const int*   batch = (const int*)d_in[2];
    const float* W_t   = (const float*)d_in[3];
    const float* b_t   = (const float*)d_in[4];
    const float* bn0_g = (const float*)d_in[5];
    const float* bn0_b = (const float*)d_in[6];
    const float* W1    = (const float*)d_in[7];
    const float* b1    = (const float*)d_in[8];
    const float* W2    = (const float*)d_in[9];
    const float* b2    = (const float*)d_in[10];
    const float* bng   = (const float*)d_in[11];
    const float* bnb   = (const float*)d_in[12];
    float* out = (float*)d_out;

    const size_t NM = (size_t)N_NODES * NHID;
    const size_t need_bytes =
        (2 * NM + 4 * 128) * sizeof(float) +        // z, c1, stats
        NM * sizeof(__half) +                        // y
        (size_t)((N_GRAPHS + 1) + N_NODES + (N_NODES + 1) + N_NODES + N_EDGES +
                 SCAN_BLOCKS) * sizeof(int);
    if (ws_size < need_bytes) return;

    float* zbuf  = (float*)d_ws;
    float* cbuf  = zbuf + NM;
    float* stats = cbuf + NM;                  // 4 stages x 128 floats
    __half* y    = (__half*)(stats + 4 * 128); // NM halfs
    int* offs      = (int*)(y + NM);           // 65
    int* deg       = offs + N_GRAPHS + 1;      // N
    int* row_start = deg + N_NODES;            // N+1
    int* cursor    = row_start + N_NODES + 1;  // N
    int* esrc      = cursor + N_NODES;         // E
    int* part      = esrc + N_EDGES;           // SCAN_BLOCKS

    const int* src = ei;
    const int* dst = ei + N_EDGES;

    // --- setup ---
    k_zero<<<(N_NODES + 255) / 256, 256, 0, stream>>>(stats, out, deg);
    k_deg<<<(N_EDGES + 255) / 256, 256, 0, stream>>>(dst, deg);
    k_offs<<<1, 128, 0, stream>>>(batch, offs);
    k_scan_partial<<<SCAN_BLOCKS, 1024, 0, stream>>>(deg, part);
    k_scan_base<<<1, 128, 0, stream>>>(part);
    k_scan_final<<<SCAN_BLOCKS, 1024, 0, stream>>>(deg, part, row_start, cursor);
    k_fill<<<(N_EDGES + 255) / 256, 256, 0, stream>>>(src, dst, cursor, esrc);

    // --- transform: y0 = x @ W_t + b_t (stats stage 0), BN folded downstream
    k_gemm<NFEAT, 64, 4, false, true, true>
        <<<(N_NODES + 63) / 64, 256, 0, stream>>>(x, W_t, b_t, y, stats, N_NODES);
    k_pool<<<64 * POOL_SLICES, 256, 0, stream>>>(y, offs, stats, bn0_g, bn0_b, out);

    // --- GIN layers ---
    for (int i = 0; i < NLAYER; ++i) {
        const float* sg = (i == 0) ? bn0_g : bng + (i - 1) * NHID;
        const float* sb = (i == 0) ? bn0_b : bnb + (i - 1) * NHID;
        k_agg<<<(N_NODES * 32 + 255) / 256, 256, 0, stream>>>(
            y, row_start, esrc, stats + i * 128, sg, sb, zbuf);
        k_gemm<NHID, 128, 8, true, false, false>
            <<<(N_NODES + 127) / 128, 256, 0, stream>>>(zbuf, W1 + i * NHID * NHID,
                                                        b1 + i * NHID, cbuf, nullptr,
                                                        N_NODES);
        k_gemm<NHID, 128, 8, true, true, true>
            <<<(N_NODES + 127) / 128, 256, 0, stream>>>(cbuf, W2 + i * NHID * NHID,
                                                        b2 + i * NHID, y,
                                                        stats + (1 + i) * 128, N_NODES);
        k_pool<<<64 * POOL_SLICES, 256, 0, stream>>>(y, offs, stats + (1 + i) * 128,
                                                     bng + i * NHID, bnb + i * NHID, out);
    }
}

// Round 8
// 618.508 us; speedup vs baseline: 2.6540x; 1.2118x over previous
//
#include <hip/hip_runtime.h>
#include <hip/hip_fp16.h>

#define N_NODES 100000
#define N_EDGES 1600000
#define NFEAT 128
#define NHID 64
#define N_GRAPHS 64
#define NLAYER 3
#define BN_EPS 1e-5f
#define POOL_SLICES 8
#define BW 512                                  // bucket node width
#define NBUCK ((N_NODES + BW - 1) / BW)         // 196
#define NBLK1 196                               // edge-chunk blocks
#define CH1 ((N_EDGES + NBLK1 - 1) / NBLK1)     // 8164

// ---------------------------------------------------------------- zero misc
__global__ void k_zero(float* __restrict__ stats, float* __restrict__ out) {
    int i = blockIdx.x * 256 + threadIdx.x;
    if (i < 4 * 128) stats[i] = 0.f;
    if (i < N_GRAPHS * NHID) out[i] = 0.f;
}

// ---------------------------------------- graph offsets via binary search
__global__ void k_offs(const int* __restrict__ batch, int* __restrict__ offs) {
    int t = threadIdx.x;
    if (t > N_GRAPHS) return;
    int lo = 0, hi = N_NODES;
    while (lo < hi) {
        int mid = (lo + hi) >> 1;
        if (batch[mid] < t) lo = mid + 1; else hi = mid;
    }
    offs[t] = lo;
}

// ----------------------------------- CSR build P1: per-(block,bucket) counts
// (replaces k_deg+k_fill: 1.6M global atomics each ~100+125us. Zero global
//  atomics here: LDS histogram -> plain stores.)
__global__ __launch_bounds__(256) void k_bincount(const int* __restrict__ dst,
                                                  int* __restrict__ cnt) {
    __shared__ int h[NBUCK];
    int t = threadIdx.x, b = blockIdx.x;
    for (int i = t; i < NBUCK; i += 256) h[i] = 0;
    __syncthreads();
    int lo = b * CH1, hi = min(lo + CH1, N_EDGES);
    for (int e = lo + t; e < hi; e += 256) {
        int d = min(max(dst[e], 0), N_NODES - 1);
        atomicAdd(&h[d >> 9], 1);
    }
    __syncthreads();
    for (int i = t; i < NBUCK; i += 256) cnt[b * NBUCK + i] = h[i];
}

// ----------------------------------- CSR build P2: scan count matrix
__global__ __launch_bounds__(256) void k_binscan(int* __restrict__ cnt,
                                                 int* __restrict__ bbase,
                                                 int* __restrict__ row_start) {
    __shared__ int tot[NBUCK];
    int t = threadIdx.x;
    if (t < NBUCK) {
        int acc = 0;
        for (int blk = 0; blk < NBLK1; ++blk) {
            int idx = blk * NBUCK + t;
            int v = cnt[idx];
            cnt[idx] = acc;      // intra-bucket exclusive prefix over blocks
            acc += v;
        }
        tot[t] = acc;
    }
    __syncthreads();
    if (t == 0) {
        int acc = 0;
        for (int i = 0; i < NBUCK; ++i) { bbase[i] = acc; acc += tot[i]; }
        bbase[NBUCK] = acc;              // == N_EDGES
        row_start[N_NODES] = N_EDGES;
    }
}

// ----------------------------------- CSR build P3: stage edges by bucket
// stage word = src (17 bits) | local_dst (9 bits) << 17
__global__ __launch_bounds__(256) void k_binstage(const int* __restrict__ src,
                                                  const int* __restrict__ dst,
                                                  const int* __restrict__ cnt,
                                                  const int* __restrict__ bbase,
                                                  int* __restrict__ stage) {
    __shared__ int cur[NBUCK];
    int t = threadIdx.x, b = blockIdx.x;
    for (int i = t; i < NBUCK; i += 256)
        cur[i] = bbase[i] + cnt[b * NBUCK + i];   // block-exclusive range
    __syncthreads();
    int lo = b * CH1, hi = min(lo + CH1, N_EDGES);
    for (int e = lo + t; e < hi; e += 256) {
        int d = min(max(dst[e], 0), N_NODES - 1);
        int s = min(max(src[e], 0), N_NODES - 1);
        int bk = d >> 9;
        int slot = atomicAdd(&cur[bk], 1);        // LDS atomic only
        stage[slot] = s | ((d & 511) << 17);
    }
}

// ----------------------------------- CSR build P4: per-bucket local sort
// One block per bucket: LDS degree hist -> LDS scan -> row_start + esrc fill.
// esrc writes land in this block's private [base,end) region (no cross-XCD
// line sharing -> ~1x writeback instead of 16x).
__global__ __launch_bounds__(256) void k_binbuild(const int* __restrict__ stage,
                                                  const int* __restrict__ bbase,
                                                  int* __restrict__ row_start,
                                                  int* __restrict__ esrc) {
    __shared__ int hist[BW];
    __shared__ int wsum2[4];
    int t = threadIdx.x, b = blockIdx.x;
    int base = bbase[b], end = bbase[b + 1];
    for (int i = t; i < BW; i += 256) hist[i] = 0;
    __syncthreads();
    for (int e = base + t; e < end; e += 256)
        atomicAdd(&hist[(unsigned)stage[e] >> 17], 1);
    __syncthreads();
    // exclusive scan of hist[512] with 256 threads (pair per thread)
    int a = hist[2 * t], c = hist[2 * t + 1];
    int p = a + c;
    int lane = t & 63, w = t >> 6;
    int incl = p;
    for (int off = 1; off < 64; off <<= 1) {
        int n = __shfl_up(incl, off);
        if (lane >= off) incl += n;
    }
    if (lane == 63) wsum2[w] = incl;
    __syncthreads();
    if (t < 4) {
        int s = wsum2[t], e2 = s;
        for (int off = 1; off < 4; off <<= 1) {
            int n = __shfl_up(e2, off, 4);
            if (t >= off) e2 += n;
        }
        wsum2[t] = e2 - s;
    }
    __syncthreads();
    int ex = incl - p + wsum2[w];
    hist[2 * t] = ex;            // becomes cursor
    hist[2 * t + 1] = ex + a;
    int g0 = b * BW + 2 * t;
    if (g0 < N_NODES) row_start[g0] = base + ex;
    if (g0 + 1 < N_NODES) row_start[g0 + 1] = base + ex + a;
    __syncthreads();
    for (int e = base + t; e < end; e += 256) {
        int v = stage[e];
        int ld = (unsigned)v >> 17, s = v & 0x1FFFF;
        int slot = atomicAdd(&hist[ld], 1);
        esrc[base + slot] = s;
    }
}

// ------------------------------------------------------------------- GEMM
// C[M,64] = act(A[M,K] @ W[K,64] + bias); optional relu; optional fused
// column sum/sumsq into stats; optional fp16 output (pre-BN activations y).
template <int K, int ROWS, int RPT, bool RELU, bool STATS, bool HALF_OUT>
__global__ __launch_bounds__(256) void k_gemm(const float* __restrict__ A,
                                              const float* __restrict__ W,
                                              const float* __restrict__ bias,
                                              void* __restrict__ Cout,
                                              float* __restrict__ stats, int M) {
    const int ROWP = ROWS + 4;
    __shared__ float At[K * ROWP];   // transposed A tile: At[k][r]
    __shared__ float Ws[K * NHID];
    __shared__ float sblk[NHID], ssblk[NHID];
    int t = threadIdx.x;
    if (STATS && t < NHID) { sblk[t] = 0.f; ssblk[t] = 0.f; }
    int row0 = blockIdx.x * ROWS;

    for (int i = t; i < K * NHID / 4; i += 256)
        ((float4*)Ws)[i] = ((const float4*)W)[i];

    const int QK = K / 4;
    for (int i = t; i < ROWS * QK; i += 256) {
        int r = i / QK, q = i - r * QK;
        int gr = row0 + r;
        float4 v = make_float4(0.f, 0.f, 0.f, 0.f);
        if (gr < M) v = ((const float4*)(A + (size_t)gr * K))[q];
        At[(4 * q + 0) * ROWP + r] = v.x;
        At[(4 * q + 1) * ROWP + r] = v.y;
        At[(4 * q + 2) * ROWP + r] = v.z;
        At[(4 * q + 3) * ROWP + r] = v.w;
    }
    __syncthreads();

    int c0 = (t & 15) * 4;
    int r0 = (t >> 4) * RPT;
    float acc[RPT][4];
#pragma unroll
    for (int i = 0; i < RPT; ++i) {
        acc[i][0] = 0.f; acc[i][1] = 0.f; acc[i][2] = 0.f; acc[i][3] = 0.f;
    }

#pragma unroll 4
    for (int k = 0; k < K; ++k) {
        float4 w = *(const float4*)&Ws[k * NHID + c0];
#pragma unroll
        for (int ii = 0; ii < RPT / 4; ++ii) {
            float4 a = *(const float4*)&At[k * ROWP + r0 + 4 * ii];
            acc[4 * ii + 0][0] = fmaf(a.x, w.x, acc[4 * ii + 0][0]);
            acc[4 * ii + 0][1] = fmaf(a.x, w.y, acc[4 * ii + 0][1]);
            acc[4 * ii + 0][2] = fmaf(a.x, w.z, acc[4 * ii + 0][2]);
            acc[4 * ii + 0][3] = fmaf(a.x, w.w, acc[4 * ii + 0][3]);
            acc[4 * ii + 1][0] = fmaf(a.y, w.x, acc[4 * ii + 1][0]);
            acc[4 * ii + 1][1] = fmaf(a.y, w.y, acc[4 * ii + 1][1]);
            acc[4 * ii + 1][2] = fmaf(a.y, w.z, acc[4 * ii + 1][2]);
            acc[4 * ii + 1][3] = fmaf(a.y, w.w, acc[4 * ii + 1][3]);
            acc[4 * ii + 2][0] = fmaf(a.z, w.x, acc[4 * ii + 2][0]);
            acc[4 * ii + 2][1] = fmaf(a.z, w.y, acc[4 * ii + 2][1]);
            acc[4 * ii + 2][2] = fmaf(a.z, w.z, acc[4 * ii + 2][2]);
            acc[4 * ii + 2][3] = fmaf(a.z, w.w, acc[4 * ii + 2][3]);
            acc[4 * ii + 3][0] = fmaf(a.w, w.x, acc[4 * ii + 3][0]);
            acc[4 * ii + 3][1] = fmaf(a.w, w.y, acc[4 * ii + 3][1]);
            acc[4 * ii + 3][2] = fmaf(a.w, w.z, acc[4 * ii + 3][2]);
            acc[4 * ii + 3][3] = fmaf(a.w, w.w, acc[4 * ii + 3][3]);
        }
    }

    float4 b4 = *(const float4*)&bias[c0];
    float sp[4] = {0.f, 0.f, 0.f, 0.f};
    float ssp[4] = {0.f, 0.f, 0.f, 0.f};
#pragma unroll
    for (int i = 0; i < RPT; ++i) {
        int gr = row0 + r0 + i;
        if (gr < M) {
            float4 v;
            v.x = acc[i][0] + b4.x;
            v.y = acc[i][1] + b4.y;
            v.z = acc[i][2] + b4.z;
            v.w = acc[i][3] + b4.w;
            if (RELU) {
                v.x = fmaxf(v.x, 0.f); v.y = fmaxf(v.y, 0.f);
                v.z = fmaxf(v.z, 0.f); v.w = fmaxf(v.w, 0.f);
            }
            if (HALF_OUT) {
                __half2* dst = (__half2*)((__half*)Cout + (size_t)gr * NHID + c0);
                dst[0] = __floats2half2_rn(v.x, v.y);
                dst[1] = __floats2half2_rn(v.z, v.w);
            } else {
                *(float4*)((float*)Cout + (size_t)gr * NHID + c0) = v;
            }
            if (STATS) {
                sp[0] += v.x; sp[1] += v.y; sp[2] += v.z; sp[3] += v.w;
                ssp[0] += v.x * v.x; ssp[1] += v.y * v.y;
                ssp[2] += v.z * v.z; ssp[3] += v.w * v.w;
            }
        }
    }

    if (STATS) {
#pragma unroll
        for (int j = 0; j < 4; ++j) {
            sp[j] += __shfl_down(sp[j], 32);
            sp[j] += __shfl_down(sp[j], 16);
            ssp[j] += __shfl_down(ssp[j], 32);
            ssp[j] += __shfl_down(ssp[j], 16);
        }
        if ((t & 63) < 16) {
#pragma unroll
            for (int j = 0; j < 4; ++j) {
                atomicAdd(&sblk[c0 + j], sp[j]);
                atomicAdd(&ssblk[c0 + j], ssp[j]);
            }
        }
        __syncthreads();
        if (t < NHID) {
            atomicAdd(&stats[t], sblk[t]);
            atomicAdd(&stats[NHID + t], ssblk[t]);
        }
    }
}

// --------------------------------------------- aggregation with folded BN
// z_i = a ∘ (y_i + Σ_{j∈N(i)} y_j) + (1+deg_i)·c,  a/c from BN stats.
// 2 nodes per wave: 32 lanes × half2 (features 2l, 2l+1).
__global__ __launch_bounds__(256) void k_agg(const __half* __restrict__ y,
                                             const int* __restrict__ row_start,
                                             const int* __restrict__ esrc,
                                             const float* __restrict__ stats,
                                             const float* __restrict__ gamma,
                                             const float* __restrict__ beta,
                                             float* __restrict__ z) {
    int w = (blockIdx.x * 256 + threadIdx.x) >> 5;
    int l = threadIdx.x & 31;
    if (w >= N_NODES) return;
    const float invN = 1.0f / (float)N_NODES;
    float m0 = stats[2 * l] * invN,     q0 = stats[NHID + 2 * l] * invN;
    float m1 = stats[2 * l + 1] * invN, q1 = stats[NHID + 2 * l + 1] * invN;
    float i0 = rsqrtf(q0 - m0 * m0 + BN_EPS);
    float i1 = rsqrtf(q1 - m1 * m1 + BN_EPS);
    float g0 = gamma[2 * l], g1 = gamma[2 * l + 1];
    float a0 = g0 * i0, a1 = g1 * i1;
    float c0 = beta[2 * l] - g0 * m0 * i0;
    float c1 = beta[2 * l + 1] - g1 * m1 * i1;

    int s = row_start[w], e = row_start[w + 1];
    float2 acc = __half22float2(((const __half2*)(y + (size_t)w * NHID))[l]);
    int i = s;
    for (; i + 1 < e; i += 2) {
        int s0 = esrc[i], s1 = esrc[i + 1];
        float2 v0 = __half22float2(((const __half2*)(y + (size_t)s0 * NHID))[l]);
        float2 v1 = __half22float2(((const __half2*)(y + (size_t)s1 * NHID))[l]);
        acc.x += v0.x; acc.y += v0.y;
        acc.x += v1.x; acc.y += v1.y;
    }
    if (i < e) {
        float2 v = __half22float2(((const __half2*)(y + (size_t)esrc[i] * NHID))[l]);
        acc.x += v.x; acc.y += v.y;
    }
    float k = (float)(1 + e - s);
    float2 zo;
    zo.x = fmaf(a0, acc.x, k * c0);
    zo.y = fmaf(a1, acc.y, k * c1);
    *(float2*)(z + (size_t)w * NHID + 2 * l) = zo;
}

// -------------------------------------- mean pooling with folded BN affine
__global__ void k_pool(const __half* __restrict__ y, const int* __restrict__ offs,
                       const float* __restrict__ stats,
                       const float* __restrict__ gamma,
                       const float* __restrict__ beta,
                       float* __restrict__ out) {
    int g = blockIdx.x & 63;
    int slice = blockIdx.x >> 6;
    int s = offs[g], e = offs[g + 1];
    int f = threadIdx.x & 31;   // feature pair
    int j = threadIdx.x >> 5;   // 8 node-lanes
    float2 acc = make_float2(0.f, 0.f);
    for (int n = s + j + slice * 8; n < e; n += 8 * POOL_SLICES) {
        float2 v = __half22float2(((const __half2*)(y + (size_t)n * NHID))[f]);
        acc.x += v.x; acc.y += v.y;
    }
    __shared__ float2 red[8][32];
    red[j][f] = acc;
    __syncthreads();
    if (threadIdx.x < 32) {
        float2 t = make_float2(0.f, 0.f);
#pragma unroll
        for (int r = 0; r < 8; ++r) { t.x += red[r][f].x; t.y += red[r][f].y; }
        int cnt = e - s;
        if (cnt > 0) {
            const float invN = 1.0f / (float)N_NODES;
            float m0 = stats[2 * f] * invN,     q0 = stats[NHID + 2 * f] * invN;
            float m1 = stats[2 * f + 1] * invN, q1 = stats[NHID + 2 * f + 1] * invN;
            float i0 = rsqrtf(q0 - m0 * m0 + BN_EPS);
            float i1 = rsqrtf(q1 - m1 * m1 + BN_EPS);
            float g0 = gamma[2 * f], g1 = gamma[2 * f + 1];
            float a0 = g0 * i0, a1 = g1 * i1;
            float c0 = beta[2 * f] - g0 * m0 * i0;
            float c1 = beta[2 * f + 1] - g1 * m1 * i1;
            float inv = 1.0f / (float)cnt;
            float add0 = a0 * t.x * inv + (slice == 0 ? c0 : 0.f);
            float add1 = a1 * t.y * inv + (slice == 0 ? c1 : 0.f);
            atomicAdd(&out[g * NHID + 2 * f], add0);
            atomicAdd(&out[g * NHID + 2 * f + 1], add1);
        }
    }
}

// ------------------------------------------------------------------- host
extern "C" void kernel_launch(void* const* d_in, const int* in_sizes, int n_in,
                              void* d_out, int out_size, void* d_ws, size_t ws_size,
                              hipStream_t stream) {
    const float* x     = (const float*)d_in[0];
    const int*   ei    = (const int*)d_in[1];
    const int*   batch = (const int*)d_in[2];
    const float* W_t   = (const float*)d_in[3];
    const float* b_t   = (const float*)d_in[4];
    const float* bn0_g = (const float*)d_in[5];
    const float* bn0_b = (const float*)d_in[6];
    const float* W1    = (const float*)d_in[7];
    const float* b1    = (const float*)d_in[8];
    const float* W2    = (const float*)d_in[9];
    const float* b2    = (const float*)d_in[10];
    const float* bng   = (const float*)d_in[11];
    const float* bnb   = (const float*)d_in[12];
    float* out = (float*)d_out;

    const size_t NM = (size_t)N_NODES * NHID;
    const size_t need_bytes =
        (2 * NM + 4 * 128) * sizeof(float) +   // z, c1, stats
        NM * sizeof(__half) +                   // y
        (size_t)((N_GRAPHS + 1) + (N_NODES + 1) + N_EDGES + N_EDGES +
                 NBLK1 * NBUCK + (NBUCK + 1)) * sizeof(int);
    if (ws_size < need_bytes) return;

    float* zbuf  = (float*)d_ws;
    float* cbuf  = zbuf + NM;
    float* stats = cbuf + NM;                  // 4 stages x 128 floats
    __half* y    = (__half*)(stats + 4 * 128); // NM halfs
    int* offs      = (int*)(y + NM);           // 65
    int* row_start = offs + N_GRAPHS + 1;      // N+1
    int* esrc      = row_start + N_NODES + 1;  // E
    int* stage     = esrc + N_EDGES;           // E
    int* cnt       = stage + N_EDGES;          // NBLK1*NBUCK
    int* bbase     = cnt + NBLK1 * NBUCK;      // NBUCK+1

    const int* src = ei;
    const int* dst = ei + N_EDGES;

    // --- setup: zero, offsets, atomic-free binned CSR build ---
    k_zero<<<(N_GRAPHS * NHID + 255) / 256, 256, 0, stream>>>(stats, out);
    k_offs<<<1, 128, 0, stream>>>(batch, offs);
    k_bincount<<<NBLK1, 256, 0, stream>>>(dst, cnt);
    k_binscan<<<1, 256, 0, stream>>>(cnt, bbase, row_start);
    k_binstage<<<NBLK1, 256, 0, stream>>>(src, dst, cnt, bbase, stage);
    k_binbuild<<<NBUCK, 256, 0, stream>>>(stage, bbase, row_start, esrc);

    // --- transform: y0 = x @ W_t + b_t (stats stage 0), BN folded downstream
    k_gemm<NFEAT, 64, 4, false, true, true>
        <<<(N_NODES + 63) / 64, 256, 0, stream>>>(x, W_t, b_t, y, stats, N_NODES);
    k_pool<<<64 * POOL_SLICES, 256, 0, stream>>>(y, offs, stats, bn0_g, bn0_b, out);

    // --- GIN layers ---
    for (int i = 0; i < NLAYER; ++i) {
        const float* sg = (i == 0) ? bn0_g : bng + (i - 1) * NHID;
        const float* sb = (i == 0) ? bn0_b : bnb + (i - 1) * NHID;
        k_agg<<<(N_NODES * 32 + 255) / 256, 256, 0, stream>>>(
            y, row_start, esrc, stats + i * 128, sg, sb, zbuf);
        k_gemm<NHID, 128, 8, true, false, false>
            <<<(N_NODES + 127) / 128, 256, 0, stream>>>(zbuf, W1 + i * NHID * NHID,
                                                        b1 + i * NHID, cbuf, nullptr,
                                                        N_NODES);
        k_gemm<NHID, 128, 8, true, true, true>
            <<<(N_NODES + 127) / 128, 256, 0, stream>>>(cbuf, W2 + i * NHID * NHID,
                                                        b2 + i * NHID, y,
                                                        stats + (1 + i) * 128, N_NODES);
        k_pool<<<64 * POOL_SLICES, 256, 0, stream>>>(y, offs, stats + (1 + i) * 128,
                                                     bng + i * NHID, bnb + i * NHID, out);
    }
}